// Round 1
// baseline (809.565 us; speedup 1.0000x reference)
//
#include <hip/hip_runtime.h>

#define F_IN 128
#define HID 64
#define C_OUT 40

// ---- degree histogram over dst (self-loop added as +1 later) ----
__global__ void deg_kernel(const int* __restrict__ dst, int E, int* __restrict__ deg) {
    int e = blockIdx.x * blockDim.x + threadIdx.x;
    if (e < E) atomicAdd(&deg[dst[e]], 1);
}

__global__ void dinv_kernel(const int* __restrict__ deg, float* __restrict__ dinv, int N) {
    int i = blockIdx.x * blockDim.x + threadIdx.x;
    if (i < N) dinv[i] = rsqrtf((float)(deg[i] + 1));
}

// ---- GEMM1: y[N,64] = (x[N,128] @ W[128,64]) * dinv[row] ----
__global__ __launch_bounds__(256) void gemm1_kernel(
    const float* __restrict__ x, const float* __restrict__ W,
    const float* __restrict__ dinv, float* __restrict__ y, int N)
{
    __shared__ float Ws[F_IN * HID];   // 32 KB
    __shared__ float Xs[16 * F_IN];    // 8 KB
    int t = threadIdx.x;
    #pragma unroll
    for (int i = 0; i < (F_IN * HID) / 256; ++i) Ws[i * 256 + t] = W[i * 256 + t];
    int r0 = blockIdx.x * 16;
    #pragma unroll
    for (int i = 0; i < (16 * F_IN) / 256; ++i) {
        int idx = i * 256 + t; int r = idx >> 7; int c = idx & 127;
        Xs[idx] = (r0 + r < N) ? x[(size_t)(r0 + r) * F_IN + c] : 0.f;
    }
    __syncthreads();
    int r = t >> 4, cg = t & 15;
    float acc[4] = {0.f, 0.f, 0.f, 0.f};
    for (int k = 0; k < F_IN; ++k) {
        float a = Xs[r * F_IN + k];
        #pragma unroll
        for (int j = 0; j < 4; ++j) acc[j] += a * Ws[k * HID + cg * 4 + j];
    }
    int gr = r0 + r;
    if (gr < N) {
        float di = dinv[gr];
        #pragma unroll
        for (int j = 0; j < 4; ++j) y[(size_t)gr * HID + cg * 4 + j] = acc[j] * di;
    }
}

// ---- GEMM2: y[N,40] = (relu(h[N,64]) @ W[64,40]) * dinv[row] ----
__global__ __launch_bounds__(256) void gemm2_kernel(
    const float* __restrict__ h, const float* __restrict__ W,
    const float* __restrict__ dinv, float* __restrict__ y, int N)
{
    __shared__ float Ws[HID * C_OUT];  // 10 KB
    __shared__ float Xs[16 * HID];     // 4 KB
    int t = threadIdx.x;
    for (int idx = t; idx < HID * C_OUT; idx += 256) Ws[idx] = W[idx];
    int r0 = blockIdx.x * 16;
    #pragma unroll
    for (int i = 0; i < (16 * HID) / 256; ++i) {
        int idx = i * 256 + t; int r = idx >> 6; int c = idx & 63;
        float v = (r0 + r < N) ? h[(size_t)(r0 + r) * HID + c] : 0.f;
        Xs[idx] = fmaxf(v, 0.f);
    }
    __syncthreads();
    int r = t >> 4, cg = t & 15;
    if (cg < 10) {
        float acc[4] = {0.f, 0.f, 0.f, 0.f};
        for (int k = 0; k < HID; ++k) {
            float a = Xs[r * HID + k];
            #pragma unroll
            for (int j = 0; j < 4; ++j) acc[j] += a * Ws[k * C_OUT + cg * 4 + j];
        }
        int gr = r0 + r;
        if (gr < N) {
            float di = dinv[gr];
            #pragma unroll
            for (int j = 0; j < 4; ++j) y[(size_t)gr * C_OUT + cg * 4 + j] = acc[j] * di;
        }
    }
}

// ---- edge scatter-add, 64 features: one 64-lane group per edge ----
__global__ void scatter64_kernel(const int* __restrict__ src, const int* __restrict__ dst,
                                 const float* __restrict__ y, float* __restrict__ acc, int E)
{
    long long tid = (long long)blockIdx.x * blockDim.x + threadIdx.x;
    int e = (int)(tid >> 6); int f = (int)(tid & 63);
    if (e < E) {
        int s = src[e], d = dst[e];
        atomicAdd(&acc[(size_t)d * HID + f], y[(size_t)s * HID + f]);
    }
}

// ---- edge scatter-add, 40 features (lanes 40..63 idle) ----
__global__ void scatter40_kernel(const int* __restrict__ src, const int* __restrict__ dst,
                                 const float* __restrict__ y, float* __restrict__ acc, int E)
{
    long long tid = (long long)blockIdx.x * blockDim.x + threadIdx.x;
    int e = (int)(tid >> 6); int f = (int)(tid & 63);
    if (e < E && f < C_OUT) {
        int s = src[e], d = dst[e];
        atomicAdd(&acc[(size_t)d * C_OUT + f], y[(size_t)s * C_OUT + f]);
    }
}

// ---- finalize layer1: h = (acc + y_self) * dinv + b  (pre-relu kept; relu at GEMM2 load) ----
__global__ void finalize1_kernel(float* __restrict__ h, const float* __restrict__ y,
                                 const float* __restrict__ dinv, const float* __restrict__ b, int N)
{
    int tid = blockIdx.x * blockDim.x + threadIdx.x;
    int i = tid >> 6, c = tid & 63;
    if (i < N) h[tid] = (h[tid] + y[tid]) * dinv[i] + b[c];
}

// ---- finalize layer2 into d_out ----
__global__ void finalize2_kernel(float* __restrict__ out, const float* __restrict__ y,
                                 const float* __restrict__ dinv, const float* __restrict__ b, int N)
{
    int tid = blockIdx.x * blockDim.x + threadIdx.x;
    if (tid < N * C_OUT) {
        int i = tid / C_OUT, c = tid - i * C_OUT;
        out[tid] = (out[tid] + y[tid]) * dinv[i] + b[c];
    }
}

extern "C" void kernel_launch(void* const* d_in, const int* in_sizes, int n_in,
                              void* d_out, int out_size, void* d_ws, size_t ws_size,
                              hipStream_t stream)
{
    const float* x  = (const float*)d_in[0];
    const int*   ei = (const int*)d_in[1];
    const float* W1 = (const float*)d_in[2];
    const float* b1 = (const float*)d_in[3];
    const float* W2 = (const float*)d_in[4];
    const float* b2 = (const float*)d_in[5];
    float* out = (float*)d_out;

    int N = in_sizes[0] / F_IN;
    int E = in_sizes[1] / 2;
    const int* src = ei;
    const int* dst = ei + E;

    char* ws = (char*)d_ws;
    float* y1   = (float*)ws;  ws += (size_t)N * HID * 4;
    float* h1   = (float*)ws;  ws += (size_t)N * HID * 4;
    float* y2   = (float*)ws;  ws += (size_t)N * C_OUT * 4;
    float* dinv = (float*)ws;  ws += (size_t)N * 4;
    int*   deg  = (int*)ws;    ws += (size_t)N * 4;

    hipMemsetAsync(h1, 0, (size_t)N * HID * 4, stream);
    hipMemsetAsync(out, 0, (size_t)N * C_OUT * 4, stream);
    hipMemsetAsync(deg, 0, (size_t)N * 4, stream);

    deg_kernel<<<(E + 255) / 256, 256, 0, stream>>>(dst, E, deg);
    dinv_kernel<<<(N + 255) / 256, 256, 0, stream>>>(deg, dinv, N);

    // layer 1
    gemm1_kernel<<<(N + 15) / 16, 256, 0, stream>>>(x, W1, dinv, y1, N);
    {
        long long total = (long long)E * 64;
        scatter64_kernel<<<(int)((total + 255) / 256), 256, 0, stream>>>(src, dst, y1, h1, E);
    }
    finalize1_kernel<<<(N * HID + 255) / 256, 256, 0, stream>>>(h1, y1, dinv, b1, N);

    // layer 2
    gemm2_kernel<<<(N + 15) / 16, 256, 0, stream>>>(h1, W2, dinv, y2, N);
    {
        long long total = (long long)E * 64;
        scatter40_kernel<<<(int)((total + 255) / 256), 256, 0, stream>>>(src, dst, y2, out, E);
    }
    finalize2_kernel<<<(N * C_OUT + 255) / 256, 256, 0, stream>>>(out, y2, dinv, b2, N);
}

// Round 2
// 468.338 us; speedup vs baseline: 1.7286x; 1.7286x over previous
//
#include <hip/hip_runtime.h>

#define F_IN 128
#define HID 64
#define C_OUT 40

// ---- degree histogram over dst ----
__global__ void deg_kernel(const int* __restrict__ dst, int E, int* __restrict__ deg) {
    int e = blockIdx.x * blockDim.x + threadIdx.x;
    if (e < E) atomicAdd(&deg[dst[e]], 1);
}

__global__ void dinv_kernel(const int* __restrict__ deg, float* __restrict__ dinv, int N) {
    int i = blockIdx.x * blockDim.x + threadIdx.x;
    if (i < N) dinv[i] = rsqrtf((float)(deg[i] + 1));   // +1 = self-loop
}

// ---- prefix sum: A) per-block (1024 elems) ----
__global__ __launch_bounds__(256) void scanA_kernel(const int* __restrict__ deg,
    int* __restrict__ rowptr, int* __restrict__ bsum, int N)
{
    __shared__ int lds[256];
    int t = threadIdx.x;
    int base = blockIdx.x * 1024 + t * 4;
    int v[4];
    #pragma unroll
    for (int k = 0; k < 4; ++k) v[k] = (base + k < N) ? deg[base + k] : 0;
    int tsum = v[0] + v[1] + v[2] + v[3];
    lds[t] = tsum; __syncthreads();
    for (int off = 1; off < 256; off <<= 1) {
        int val = lds[t];
        int add = (t >= off) ? lds[t - off] : 0;
        __syncthreads();
        lds[t] = val + add;
        __syncthreads();
    }
    int excl = lds[t] - tsum;
    if (t == 255) bsum[blockIdx.x] = lds[255];
    int run = excl;
    #pragma unroll
    for (int k = 0; k < 4; ++k) { if (base + k < N) rowptr[base + k] = run; run += v[k]; }
}

// ---- B) scan the block sums (single wave) ----
__global__ void scanB_kernel(int* __restrict__ bsum, int nb) {
    int lane = threadIdx.x;   // 64 threads
    int carry = 0;
    for (int base = 0; base < nb; base += 64) {
        int i = base + lane;
        int v = (i < nb) ? bsum[i] : 0;
        int incl = v;
        for (int off = 1; off < 64; off <<= 1) {
            int u = __shfl_up(incl, off);
            if (lane >= off) incl += u;
        }
        if (i < nb) bsum[i] = incl - v + carry;
        carry += __shfl(incl, 63);
    }
}

// ---- C) add block offsets ----
__global__ void scanC_kernel(int* __restrict__ rowptr, const int* __restrict__ bsum, int N) {
    int i = blockIdx.x * blockDim.x + threadIdx.x;
    if (i < N) rowptr[i] += bsum[i >> 10];
}

// ---- fill CSR: rowptr becomes end-pointer ----
__global__ void fill_kernel(const int* __restrict__ src, const int* __restrict__ dst, int E,
                            int* __restrict__ rowptr, int* __restrict__ csr)
{
    int e = blockIdx.x * blockDim.x + threadIdx.x;
    if (e < E) {
        int slot = atomicAdd(&rowptr[dst[e]], 1);
        csr[slot] = src[e];
    }
}

// ---- GEMM1: y[N,64] = (x[N,128] @ W[128,64]) * dinv[row] ----
__global__ __launch_bounds__(256) void gemm1_kernel(
    const float* __restrict__ x, const float* __restrict__ W,
    const float* __restrict__ dinv, float* __restrict__ y, int N)
{
    __shared__ float Ws[F_IN * HID];
    __shared__ float Xs[16 * F_IN];
    int t = threadIdx.x;
    #pragma unroll
    for (int i = 0; i < (F_IN * HID) / 256; ++i) Ws[i * 256 + t] = W[i * 256 + t];
    int r0 = blockIdx.x * 16;
    #pragma unroll
    for (int i = 0; i < (16 * F_IN) / 256; ++i) {
        int idx = i * 256 + t; int r = idx >> 7; int c = idx & 127;
        Xs[idx] = (r0 + r < N) ? x[(size_t)(r0 + r) * F_IN + c] : 0.f;
    }
    __syncthreads();
    int r = t >> 4, cg = t & 15;
    float acc[4] = {0.f, 0.f, 0.f, 0.f};
    for (int k = 0; k < F_IN; ++k) {
        float a = Xs[r * F_IN + k];
        #pragma unroll
        for (int j = 0; j < 4; ++j) acc[j] += a * Ws[k * HID + cg * 4 + j];
    }
    int gr = r0 + r;
    if (gr < N) {
        float di = dinv[gr];
        #pragma unroll
        for (int j = 0; j < 4; ++j) y[(size_t)gr * HID + cg * 4 + j] = acc[j] * di;
    }
}

// ---- agg1: h[d] = relu((sum_{s->d} y[s] + y[d]) * dinv[d] + b)  (relu fused) ----
__global__ __launch_bounds__(256) void agg1_kernel(
    const int* __restrict__ csr, const int* __restrict__ endp, const int* __restrict__ deg,
    const float* __restrict__ y, const float* __restrict__ dinv,
    const float* __restrict__ b, float* __restrict__ h, int N)
{
    int node = blockIdx.x * 4 + (threadIdx.x >> 6);
    if (node >= N) return;
    int f = threadIdx.x & 63;
    int end = endp[node];
    int beg = end - deg[node];
    float acc = y[(size_t)node * HID + f];
    int j = beg;
    for (; j + 1 < end; j += 2) {
        int s0 = csr[j], s1 = csr[j + 1];
        float a0 = y[(size_t)s0 * HID + f];
        float a1 = y[(size_t)s1 * HID + f];
        acc += a0; acc += a1;
    }
    if (j < end) acc += y[(size_t)csr[j] * HID + f];
    h[(size_t)node * HID + f] = fmaxf(acc * dinv[node] + b[f], 0.f);
}

// ---- GEMM2: y2[N,64-stride] = (h[N,64] @ W[64,40]) * dinv[row]  (h already relu'd) ----
__global__ __launch_bounds__(256) void gemm2_kernel(
    const float* __restrict__ h, const float* __restrict__ W,
    const float* __restrict__ dinv, float* __restrict__ y, int N)
{
    __shared__ float Ws[HID * C_OUT];
    __shared__ float Xs[16 * HID];
    int t = threadIdx.x;
    for (int idx = t; idx < HID * C_OUT; idx += 256) Ws[idx] = W[idx];
    int r0 = blockIdx.x * 16;
    #pragma unroll
    for (int i = 0; i < (16 * HID) / 256; ++i) {
        int idx = i * 256 + t; int r = idx >> 6; int c = idx & 63;
        Xs[idx] = (r0 + r < N) ? h[(size_t)(r0 + r) * HID + c] : 0.f;
    }
    __syncthreads();
    int r = t >> 4, cg = t & 15;
    if (cg < 10) {
        float acc[4] = {0.f, 0.f, 0.f, 0.f};
        for (int k = 0; k < HID; ++k) {
            float a = Xs[r * HID + k];
            #pragma unroll
            for (int j = 0; j < 4; ++j) acc[j] += a * Ws[k * C_OUT + cg * 4 + j];
        }
        int gr = r0 + r;
        if (gr < N) {
            float di = dinv[gr];
            #pragma unroll
            for (int j = 0; j < 4; ++j) y[(size_t)gr * 64 + cg * 4 + j] = acc[j] * di;
        }
    }
}

// ---- agg2: out[d] = (sum y2[s] + y2[d]) * dinv[d] + b2 ----
__global__ __launch_bounds__(256) void agg2_kernel(
    const int* __restrict__ csr, const int* __restrict__ endp, const int* __restrict__ deg,
    const float* __restrict__ y, const float* __restrict__ dinv,
    const float* __restrict__ b, float* __restrict__ out, int N)
{
    int node = blockIdx.x * 4 + (threadIdx.x >> 6);
    int f = threadIdx.x & 63;
    if (node >= N || f >= C_OUT) return;
    int end = endp[node];
    int beg = end - deg[node];
    float acc = y[(size_t)node * 64 + f];
    int j = beg;
    for (; j + 1 < end; j += 2) {
        int s0 = csr[j], s1 = csr[j + 1];
        float a0 = y[(size_t)s0 * 64 + f];
        float a1 = y[(size_t)s1 * 64 + f];
        acc += a0; acc += a1;
    }
    if (j < end) acc += y[(size_t)csr[j] * 64 + f];
    out[(size_t)node * C_OUT + f] = acc * dinv[node] + b[f];
}

extern "C" void kernel_launch(void* const* d_in, const int* in_sizes, int n_in,
                              void* d_out, int out_size, void* d_ws, size_t ws_size,
                              hipStream_t stream)
{
    const float* x  = (const float*)d_in[0];
    const int*   ei = (const int*)d_in[1];
    const float* W1 = (const float*)d_in[2];
    const float* b1 = (const float*)d_in[3];
    const float* W2 = (const float*)d_in[4];
    const float* b2 = (const float*)d_in[5];
    float* out = (float*)d_out;

    int N = in_sizes[0] / F_IN;
    int E = in_sizes[1] / 2;
    const int* src = ei;
    const int* dst = ei + E;

    char* ws = (char*)d_ws;
    float* y1     = (float*)ws;  ws += (size_t)N * HID * 4;     // also reused as y2 (stride 64)
    float* h1     = (float*)ws;  ws += (size_t)N * HID * 4;
    float* dinv   = (float*)ws;  ws += (size_t)N * 4;
    int*   deg    = (int*)ws;    ws += (size_t)N * 4;
    int*   rowptr = (int*)ws;    ws += (size_t)N * 4;
    int*   csr    = (int*)ws;    ws += (size_t)E * 4;
    int*   bsum   = (int*)ws;    ws += 1024;

    int nbScan = (N + 1023) / 1024;

    hipMemsetAsync(deg, 0, (size_t)N * 4, stream);
    deg_kernel<<<(E + 255) / 256, 256, 0, stream>>>(dst, E, deg);
    dinv_kernel<<<(N + 255) / 256, 256, 0, stream>>>(deg, dinv, N);

    scanA_kernel<<<nbScan, 256, 0, stream>>>(deg, rowptr, bsum, N);
    scanB_kernel<<<1, 64, 0, stream>>>(bsum, nbScan);
    scanC_kernel<<<(N + 255) / 256, 256, 0, stream>>>(rowptr, bsum, N);
    fill_kernel<<<(E + 255) / 256, 256, 0, stream>>>(src, dst, E, rowptr, csr);
    // rowptr is now the END pointer per node

    // layer 1
    gemm1_kernel<<<(N + 15) / 16, 256, 0, stream>>>(x, W1, dinv, y1, N);
    agg1_kernel<<<(N + 3) / 4, 256, 0, stream>>>(csr, rowptr, deg, y1, dinv, b1, h1, N);

    // layer 2 (y2 aliases y1; stride 64)
    gemm2_kernel<<<(N + 15) / 16, 256, 0, stream>>>(h1, W2, dinv, y1, N);
    agg2_kernel<<<(N + 3) / 4, 256, 0, stream>>>(csr, rowptr, deg, y1, dinv, b2, out, N);
}